// Round 1
// baseline (4224.918 us; speedup 1.0000x reference)
//
#include <hip/hip_runtime.h>

// GCN: out = GraphConv(relu(GraphConv(X, W1, b1)), W2, b2), norm='right'
// Layer1 uses aggregate-then-GEMM (linearity); Layer2 uses GEMM-then-aggregate.

static __device__ __forceinline__ void atomAddF(float* p, float v) {
    __hip_atomic_fetch_add(p, v, __ATOMIC_RELAXED, __HIP_MEMORY_SCOPE_AGENT);
}

// Edge scatter: agg[dst] += X[src] over `C4*4` channels, optional degree count.
template<int C4, bool DO_DEG>
__global__ __launch_bounds__(256) void k_scatter(
    const float* __restrict__ X, const int* __restrict__ src,
    const int* __restrict__ dst, float* __restrict__ agg,
    float* __restrict__ degf, int n_edges, int in_stride)
{
    const int t = blockIdx.x * 256 + threadIdx.x;
    constexpr int SHIFT = (C4 == 32) ? 5 : 4;
    const int e = t >> SHIFT;
    if (e >= n_edges) return;
    const int lane = t & (C4 - 1);
    const int c = lane << 2;
    const int s = src[e];
    const int d = dst[e];
    const float4 v = *(const float4*)(X + (size_t)s * in_stride + c);
    float* p = agg + (size_t)d * (C4 * 4) + c;
    atomAddF(p + 0, v.x);
    atomAddF(p + 1, v.y);
    atomAddF(p + 2, v.z);
    atomAddF(p + 3, v.w);
    if (DO_DEG && lane == 0) atomAddF(degf + d, 1.0f);
}

__global__ __launch_bounds__(256) void k_deginv(
    const float* __restrict__ degf, float* __restrict__ dinv, int n)
{
    const int i = blockIdx.x * 256 + threadIdx.x;
    if (i < n) dinv[i] = 1.0f / fmaxf(degf[i], 1.0f);
}

// C[row, 0:OUTC] = (optional deg_inv[row] *) A[row, 0:128] @ W[128, OUTC]
// (+ optional bias & relu). Block = 64 rows, 256 threads. In-place safe
// (block stages its 64 rows into LDS fully before any write).
template<int OUTC, bool PRESCALE, bool BIASRELU>
__global__ __launch_bounds__(256) void k_gemm(
    const float* __restrict__ A, const float* __restrict__ W,
    const float* __restrict__ bias, const float* __restrict__ deg_inv,
    float* __restrict__ C, int N, int out_stride)
{
    __shared__ float As[64][128];
    const int tid = threadIdx.x;
    const int row0 = blockIdx.x * 64;

    // Stage A tile (64x128 f32), optional row prescale.
    for (int i = tid; i < 64 * 32; i += 256) {
        const int r = i >> 5;
        const int cc = (i & 31) << 2;
        const int row = row0 + r;
        float4 v = make_float4(0.f, 0.f, 0.f, 0.f);
        if (row < N) {
            v = *(const float4*)(A + (size_t)row * 128 + cc);
            if (PRESCALE) {
                const float s = deg_inv[row];
                v.x *= s; v.y *= s; v.z *= s; v.w *= s;
            }
        }
        *(float4*)&As[r][cc] = v;
    }
    __syncthreads();

    constexpr int CG = OUTC / 4;           // col groups: 32 (OUTC=128) / 16 (OUTC=64)
    constexpr int RPT = (64 * CG) / 256;   // rows per thread: 8 / 4
    const int cg = tid & (CG - 1);
    const int rg = tid / CG;
    const int c0 = cg * 4;
    const int r0 = rg * RPT;

    float acc[RPT][4];
#pragma unroll
    for (int r = 0; r < RPT; ++r)
        for (int j = 0; j < 4; ++j) acc[r][j] = 0.f;

#pragma unroll 2
    for (int k = 0; k < 128; k += 4) {
        const float4 w0 = *(const float4*)(W + (size_t)(k + 0) * OUTC + c0);
        const float4 w1 = *(const float4*)(W + (size_t)(k + 1) * OUTC + c0);
        const float4 w2 = *(const float4*)(W + (size_t)(k + 2) * OUTC + c0);
        const float4 w3 = *(const float4*)(W + (size_t)(k + 3) * OUTC + c0);
#pragma unroll
        for (int r = 0; r < RPT; ++r) {
            const float4 a = *(const float4*)&As[r0 + r][k];
            acc[r][0] = fmaf(a.x, w0.x, fmaf(a.y, w1.x, fmaf(a.z, w2.x, fmaf(a.w, w3.x, acc[r][0]))));
            acc[r][1] = fmaf(a.x, w0.y, fmaf(a.y, w1.y, fmaf(a.z, w2.y, fmaf(a.w, w3.y, acc[r][1]))));
            acc[r][2] = fmaf(a.x, w0.z, fmaf(a.y, w1.z, fmaf(a.z, w2.z, fmaf(a.w, w3.z, acc[r][2]))));
            acc[r][3] = fmaf(a.x, w0.w, fmaf(a.y, w1.w, fmaf(a.z, w2.w, fmaf(a.w, w3.w, acc[r][3]))));
        }
    }

#pragma unroll
    for (int r = 0; r < RPT; ++r) {
        const int row = row0 + r0 + r;
        if (row >= N) continue;
        float4 o = make_float4(acc[r][0], acc[r][1], acc[r][2], acc[r][3]);
        if (BIASRELU) {
            const float4 b = *(const float4*)(bias + c0);
            o.x = fmaxf(o.x + b.x, 0.f);
            o.y = fmaxf(o.y + b.y, 0.f);
            o.z = fmaxf(o.z + b.z, 0.f);
            o.w = fmaxf(o.w + b.w, 0.f);
        }
        *(float4*)(C + (size_t)row * out_stride + c0) = o;
    }
}

__global__ __launch_bounds__(256) void k_final(
    const float* __restrict__ agg2, const float* __restrict__ dinv,
    const float* __restrict__ b2, float* __restrict__ out, int N)
{
    const int t = blockIdx.x * 256 + threadIdx.x;
    if (t >= N * 16) return;
    const int n = t >> 4;
    const int c = (t & 15) << 2;
    float4 v = *(const float4*)(agg2 + (size_t)n * 64 + c);
    const float s = dinv[n];
    const float4 b = *(const float4*)(b2 + c);
    v.x = fmaf(v.x, s, b.x);
    v.y = fmaf(v.y, s, b.y);
    v.z = fmaf(v.z, s, b.z);
    v.w = fmaf(v.w, s, b.w);
    *(float4*)(out + (size_t)n * 64 + c) = v;
}

extern "C" void kernel_launch(void* const* d_in, const int* in_sizes, int n_in,
                              void* d_out, int out_size, void* d_ws, size_t ws_size,
                              hipStream_t stream)
{
    const float* X  = (const float*)d_in[0];
    const int*  src = (const int*)d_in[1];
    const int*  dst = (const int*)d_in[2];
    const float* W1 = (const float*)d_in[3];
    const float* b1 = (const float*)d_in[4];
    const float* W2 = (const float*)d_in[5];
    const float* b2 = (const float*)d_in[6];
    float* out = (float*)d_out;

    const int N = in_sizes[0] / 128;
    const int E = in_sizes[1];

    float* buf1 = (float*)d_ws;                  // N*128: agg1 -> h -> m2 (cols 0..63)
    float* agg2 = buf1 + (size_t)N * 128;        // N*64
    float* degf = agg2 + (size_t)N * 64;         // N
    float* dinv = degf + N;                      // N

    hipMemsetAsync(buf1, 0, (size_t)N * 128 * sizeof(float), stream);
    hipMemsetAsync(agg2, 0, (size_t)N * 64 * sizeof(float), stream);
    hipMemsetAsync(degf, 0, (size_t)N * sizeof(float), stream);

    // Layer 1 aggregation on raw features (+ degree count).
    {
        const long long threads = (long long)E * 32;
        const int blocks = (int)((threads + 255) / 256);
        k_scatter<32, true><<<blocks, 256, 0, stream>>>(X, src, dst, buf1, degf, E, 128);
    }
    k_deginv<<<(N + 255) / 256, 256, 0, stream>>>(degf, dinv, N);

    const int gb = (N + 63) / 64;
    // h = relu((deg_inv * agg1) @ W1 + b1), in-place in buf1.
    k_gemm<128, true, true><<<gb, 256, 0, stream>>>(buf1, W1, b1, dinv, buf1, N, 128);
    // m2 = h @ W2, written into cols 0..63 of buf1 (stride 128), in-place safe.
    k_gemm<64, false, false><<<gb, 256, 0, stream>>>(buf1, W2, nullptr, nullptr, buf1, N, 128);

    // Layer 2 aggregation on m2 (64 channels).
    {
        const long long threads = (long long)E * 16;
        const int blocks = (int)((threads + 255) / 256);
        k_scatter<16, false><<<blocks, 256, 0, stream>>>(buf1, src, dst, agg2, nullptr, E, 128);
    }
    // out = agg2 * deg_inv + b2
    k_final<<<(N * 16 + 255) / 256, 256, 0, stream>>>(agg2, dinv, b2, out, N);
}

// Round 2
// 486.167 us; speedup vs baseline: 8.6903x; 8.6903x over previous
//
#include <hip/hip_runtime.h>

// GCN via CSR-gather (no float atomics):
//   1) build CSR over dst (hist -> scan -> fill)
//   2) agg1[n] = (1/deg) * sum_{e: dst=n} X[src_e]     (gather, wave/node)
//   3) h = relu(agg1 @ W1 + b1)                        (LDS-tiled fp32 GEMM)
//   4) m2 = h @ W2
//   5) out[n] = (1/deg) * sum m2[src_e] + b2           (gather, fused epilogue)

constexpr int SCAN_B = 1024;

__global__ __launch_bounds__(256) void k_hist(
    const int* __restrict__ dst, int* __restrict__ counts, int E)
{
    const int e = blockIdx.x * 256 + threadIdx.x;
    if (e < E) atomicAdd(&counts[dst[e]], 1);
}

__global__ __launch_bounds__(SCAN_B) void k_scan_block(
    const int* __restrict__ counts, int* __restrict__ row_start,
    int* __restrict__ block_sums, int N)
{
    __shared__ int sh[SCAN_B];
    const int t = threadIdx.x;
    const int i = blockIdx.x * SCAN_B + t;
    const int v = (i < N) ? counts[i] : 0;
    sh[t] = v;
    __syncthreads();
    for (int off = 1; off < SCAN_B; off <<= 1) {
        int u = (t >= off) ? sh[t - off] : 0;
        __syncthreads();
        if (t >= off) sh[t] += u;
        __syncthreads();
    }
    if (i < N) row_start[i] = sh[t] - v;           // exclusive
    if (t == SCAN_B - 1) block_sums[blockIdx.x] = sh[t];
}

__global__ __launch_bounds__(SCAN_B) void k_scan_sums(int* __restrict__ bs, int nb)
{
    __shared__ int sh[SCAN_B];
    const int t = threadIdx.x;
    const int v = (t < nb) ? bs[t] : 0;
    sh[t] = v;
    __syncthreads();
    for (int off = 1; off < SCAN_B; off <<= 1) {
        int u = (t >= off) ? sh[t - off] : 0;
        __syncthreads();
        if (t >= off) sh[t] += u;
        __syncthreads();
    }
    if (t < nb) bs[t] = sh[t] - v;                 // exclusive
}

__global__ __launch_bounds__(SCAN_B) void k_scan_add(
    int* __restrict__ row_start, const int* __restrict__ bs,
    int* __restrict__ cursor, int N, int E)
{
    const int i = blockIdx.x * SCAN_B + threadIdx.x;
    if (i < N) {
        const int v = row_start[i] + bs[blockIdx.x];
        row_start[i] = v;
        cursor[i] = v;
    }
    if (i == 0) row_start[N] = E;
}

__global__ __launch_bounds__(256) void k_fill(
    const int* __restrict__ src, const int* __restrict__ dst,
    int* __restrict__ cursor, int* __restrict__ edge_src, int E)
{
    const int e = blockIdx.x * 256 + threadIdx.x;
    if (e < E) {
        const int p = atomicAdd(&cursor[dst[e]], 1);
        edge_src[p] = src[e];
    }
}

// One wave per node: acc = (1/deg) * sum_{j in [beg,end)} M[edge_src[j]]  (+bias)
template<int C, bool ADDBIAS>
__global__ __launch_bounds__(256) void k_agg(
    const float* __restrict__ M, const int* __restrict__ edge_src,
    const int* __restrict__ row_start, const float* __restrict__ bias,
    float* __restrict__ outp, int N)
{
    const int w = (blockIdx.x * 256 + threadIdx.x) >> 6;
    if (w >= N) return;
    const int lane = threadIdx.x & 63;
    const int beg = row_start[w];
    const int end = row_start[w + 1];
    const float inv = 1.0f / fmaxf((float)(end - beg), 1.0f);

    if (C == 128) {
        const int c = lane * 2;
        float ax = 0.f, ay = 0.f, bx = 0.f, by = 0.f;
        int j = beg;
        for (; j + 3 < end; j += 4) {
            const int s0 = edge_src[j + 0], s1 = edge_src[j + 1];
            const int s2 = edge_src[j + 2], s3 = edge_src[j + 3];
            const float2 v0 = *(const float2*)(M + (size_t)s0 * 128 + c);
            const float2 v1 = *(const float2*)(M + (size_t)s1 * 128 + c);
            const float2 v2 = *(const float2*)(M + (size_t)s2 * 128 + c);
            const float2 v3 = *(const float2*)(M + (size_t)s3 * 128 + c);
            ax += v0.x + v2.x; ay += v0.y + v2.y;
            bx += v1.x + v3.x; by += v1.y + v3.y;
        }
        for (; j < end; ++j) {
            const float2 v = *(const float2*)(M + (size_t)edge_src[j] * 128 + c);
            ax += v.x; ay += v.y;
        }
        float2 o;
        o.x = (ax + bx) * inv;
        o.y = (ay + by) * inv;
        *(float2*)(outp + (size_t)w * 128 + c) = o;
    } else {
        float a = 0.f, b = 0.f, cc = 0.f, d = 0.f;
        int j = beg;
        for (; j + 3 < end; j += 4) {
            a  += M[(size_t)edge_src[j + 0] * 64 + lane];
            b  += M[(size_t)edge_src[j + 1] * 64 + lane];
            cc += M[(size_t)edge_src[j + 2] * 64 + lane];
            d  += M[(size_t)edge_src[j + 3] * 64 + lane];
        }
        for (; j < end; ++j) a += M[(size_t)edge_src[j] * 64 + lane];
        float o = (a + b + cc + d) * inv;
        if (ADDBIAS) o += bias[lane];
        outp[(size_t)w * 64 + lane] = o;
    }
}

// C[row, 0:OUTC] = A[row, 0:128] @ W[128, OUTC] (+ bias&relu). 64 rows/block,
// 256 threads, A tile in LDS. In-place safe (full tile staged before writes).
template<int OUTC, bool BIASRELU>
__global__ __launch_bounds__(256) void k_gemm(
    const float* __restrict__ A, const float* __restrict__ W,
    const float* __restrict__ bias, float* __restrict__ C, int N, int out_stride)
{
    __shared__ float As[64][128];
    const int tid = threadIdx.x;
    const int row0 = blockIdx.x * 64;

    for (int i = tid; i < 64 * 32; i += 256) {
        const int r = i >> 5;
        const int cc = (i & 31) << 2;
        const int row = row0 + r;
        float4 v = make_float4(0.f, 0.f, 0.f, 0.f);
        if (row < N) v = *(const float4*)(A + (size_t)row * 128 + cc);
        *(float4*)&As[r][cc] = v;
    }
    __syncthreads();

    constexpr int CG = OUTC / 4;
    constexpr int RPT = (64 * CG) / 256;
    const int cg = tid & (CG - 1);
    const int rg = tid / CG;
    const int c0 = cg * 4;
    const int r0 = rg * RPT;

    float acc[RPT][4];
#pragma unroll
    for (int r = 0; r < RPT; ++r)
        for (int j = 0; j < 4; ++j) acc[r][j] = 0.f;

#pragma unroll 2
    for (int k = 0; k < 128; k += 4) {
        const float4 w0 = *(const float4*)(W + (size_t)(k + 0) * OUTC + c0);
        const float4 w1 = *(const float4*)(W + (size_t)(k + 1) * OUTC + c0);
        const float4 w2 = *(const float4*)(W + (size_t)(k + 2) * OUTC + c0);
        const float4 w3 = *(const float4*)(W + (size_t)(k + 3) * OUTC + c0);
#pragma unroll
        for (int r = 0; r < RPT; ++r) {
            const float4 a = *(const float4*)&As[r0 + r][k];
            acc[r][0] = fmaf(a.x, w0.x, fmaf(a.y, w1.x, fmaf(a.z, w2.x, fmaf(a.w, w3.x, acc[r][0]))));
            acc[r][1] = fmaf(a.x, w0.y, fmaf(a.y, w1.y, fmaf(a.z, w2.y, fmaf(a.w, w3.y, acc[r][1]))));
            acc[r][2] = fmaf(a.x, w0.z, fmaf(a.y, w1.z, fmaf(a.z, w2.z, fmaf(a.w, w3.z, acc[r][2]))));
            acc[r][3] = fmaf(a.x, w0.w, fmaf(a.y, w1.w, fmaf(a.z, w2.w, fmaf(a.w, w3.w, acc[r][3]))));
        }
    }

#pragma unroll
    for (int r = 0; r < RPT; ++r) {
        const int row = row0 + r0 + r;
        if (row >= N) continue;
        float4 o = make_float4(acc[r][0], acc[r][1], acc[r][2], acc[r][3]);
        if (BIASRELU) {
            const float4 b = *(const float4*)(bias + c0);
            o.x = fmaxf(o.x + b.x, 0.f);
            o.y = fmaxf(o.y + b.y, 0.f);
            o.z = fmaxf(o.z + b.z, 0.f);
            o.w = fmaxf(o.w + b.w, 0.f);
        }
        *(float4*)(C + (size_t)row * out_stride + c0) = o;
    }
}

extern "C" void kernel_launch(void* const* d_in, const int* in_sizes, int n_in,
                              void* d_out, int out_size, void* d_ws, size_t ws_size,
                              hipStream_t stream)
{
    const float* X  = (const float*)d_in[0];
    const int*  src = (const int*)d_in[1];
    const int*  dst = (const int*)d_in[2];
    const float* W1 = (const float*)d_in[3];
    const float* b1 = (const float*)d_in[4];
    const float* W2 = (const float*)d_in[5];
    const float* b2 = (const float*)d_in[6];
    float* out = (float*)d_out;

    const int N = in_sizes[0] / 128;
    const int E = in_sizes[1];

    float* buf1      = (float*)d_ws;                         // N*128: agg1 -> h
    float* m2        = buf1 + (size_t)N * 128;               // N*64
    int*   row_start = (int*)(m2 + (size_t)N * 64);          // N+1
    int*   cursor    = row_start + (N + 2);                  // N (doubles as counts)
    int*   block_sums= cursor + N;                           // SCAN_B
    int*   edge_src  = block_sums + SCAN_B;                  // E

    const int nb = (N + SCAN_B - 1) / SCAN_B;

    // --- build CSR over dst ---
    hipMemsetAsync(cursor, 0, (size_t)N * sizeof(int), stream);
    k_hist<<<(E + 255) / 256, 256, 0, stream>>>(dst, cursor, E);
    k_scan_block<<<nb, SCAN_B, 0, stream>>>(cursor, row_start, block_sums, N);
    k_scan_sums<<<1, SCAN_B, 0, stream>>>(block_sums, nb);
    k_scan_add<<<nb, SCAN_B, 0, stream>>>(row_start, block_sums, cursor, N, E);
    k_fill<<<(E + 255) / 256, 256, 0, stream>>>(src, dst, cursor, edge_src, E);

    // --- layer 1: gather-agg (scaled) then GEMM+bias+relu ---
    k_agg<128, false><<<(N + 3) / 4, 256, 0, stream>>>(X, edge_src, row_start, nullptr, buf1, N);
    k_gemm<128, true><<<(N + 63) / 64, 256, 0, stream>>>(buf1, W1, b1, buf1, N, 128);

    // --- layer 2: GEMM then gather-agg with fused (1/deg, +b2) epilogue ---
    k_gemm<64, false><<<(N + 63) / 64, 256, 0, stream>>>(buf1, W2, nullptr, m2, N, 64);
    k_agg<64, true><<<(N + 3) / 4, 256, 0, stream>>>(m2, edge_src, row_start, b2, out, N);
}